// Round 1
// baseline (2493.257 us; speedup 1.0000x reference)
//
#include <hip/hip_runtime.h>
#include <math.h>

#define TILE_E 32
#define THREADS 256

__device__ __forceinline__ float silu_f(float x) {
    return x / (1.0f + expf(-x));
}

// d_ws layout per edge (352 floats):
//   d0[u]        : [0   + u]        (p=0)
//   d1[u][j]     : [32  + u*3 + j]  (p=1)
//   d2[u]        : [128 + u]        (p=2)
//   d3[u][i]     : [160 + u*3 + i]  (p=3)
//   d4[u][j]     : [256 + u*3 + j]  (p=4)

__global__ __launch_bounds__(256, 2)
void fused_main(const float* __restrict__ ef,     // [E][32]
                const float* __restrict__ em2,    // [E][128]
                const float* __restrict__ nfs,    // [E][128]
                const float* __restrict__ nfr,    // [E][128]
                const float* __restrict__ Wn,     // [128][32]
                const float* __restrict__ W1,     // [96][128]
                const float* __restrict__ W2,     // [128][128]
                const float* __restrict__ W3,     // [128][5120]
                float* __restrict__ dws)          // [E][352]
{
    __shared__ __align__(16) float h2s[128][36];   // h2 t-major, padded (18.0 KB)
    __shared__ __align__(16) float scal[32][100];  // [s_send|s_recv|ef] (12.5 KB)
    __shared__ __align__(16) float Cbuf[8320];     // union region (33.3 KB):
                                                   //  nf[2][32][128] / h1[32][128]
                                                   //  w3s[32][256]   / wt[32][260]
    const int tid = threadIdx.x;
    const int e0  = blockIdx.x * TILE_E;

    float* nf  = Cbuf;   // [2][32][128]
    float* h1  = Cbuf;   // [32][128]
    float* w3s = Cbuf;   // [32][256]
    float* wt  = Cbuf;   // [32][260]

    // ---- phase 0a: stage node feats + edge feats ----
    #pragma unroll
    for (int q = 0; q < 8; ++q) {
        int idx = q * 256 + tid;          // 0..2047 (float4 units)
        int sel = idx >> 10;              // 0: sender, 1: receiver
        int e   = (idx >> 5) & 31;
        int t4  = idx & 31;               // float4 index within 128-row
        const float* src = sel ? nfr : nfs;
        float4 v = *(const float4*)(src + (size_t)(e0 + e) * 128 + t4 * 4);
        *(float4*)(nf + sel * 4096 + e * 128 + t4 * 4) = v;
    }
    #pragma unroll
    for (int q = 0; q < 4; ++q) {
        int idx = q * 256 + tid;          // 0..1023
        int e = idx >> 5, j = idx & 31;
        scal[e][64 + j] = ef[(size_t)(e0 + e) * 32 + j];
    }
    __syncthreads();

    // ---- phase 0b: s_send / s_recv ----
    #pragma unroll
    for (int q = 0; q < 8; ++q) {
        int idx = q * 256 + tid;          // 0..2047
        int sel = idx >> 10;
        int e   = (idx >> 5) & 31;
        int j   = idx & 31;
        const float* nrow = nf + sel * 4096 + e * 128;
        float acc = 0.f;
        for (int t = 0; t < 128; ++t)
            acc += nrow[t] * Wn[t * 32 + j];
        scal[e][sel * 32 + j] = acc * 0.08838834764831845f;  // 1/sqrt(128)
    }
    __syncthreads();

    // ---- phase 0c: h1 = silu(scal @ W1 / sqrt(96)) ----
    #pragma unroll
    for (int q = 0; q < 16; ++q) {
        int idx = q * 256 + tid;          // 0..4095
        int e = idx >> 7, j = idx & 127;
        float acc = 0.f;
        for (int t = 0; t < 96; ++t)
            acc += scal[e][t] * W1[t * 128 + j];
        h1[e * 128 + j] = silu_f(acc * 0.10206207261596575f); // 1/sqrt(96)
    }
    __syncthreads();

    // ---- phase 0d: h2 = silu(h1 @ W2 / sqrt(128)), stored t-major ----
    #pragma unroll
    for (int q = 0; q < 16; ++q) {
        int idx = q * 256 + tid;
        int e = idx >> 7, j = idx & 127;
        float acc = 0.f;
        for (int t = 0; t < 128; ++t)
            acc += h1[e * 128 + t] * W2[t * 128 + j];
        h2s[j][e] = silu_f(acc * 0.08838834764831845f);
    }
    __syncthreads();

    // ---- GEMM: w = h2 @ W3 / sqrt(128), fused contraction with x2 ----
    const int ct = tid & 63;   // col-quad: cols ct*4 .. ct*4+3 (of 256)
    const int et = tid >> 6;   // edge group: edges et*8 .. et*8+7 (wave-uniform)

    for (int ch = 0; ch < 20; ++ch) {
        float acc[8][4];
        #pragma unroll
        for (int i = 0; i < 8; ++i)
            #pragma unroll
            for (int c = 0; c < 4; ++c) acc[i][c] = 0.f;

        for (int ks = 0; ks < 4; ++ks) {
            __syncthreads();  // protect Cbuf (prev k-loop reads / prev epilogue)
            #pragma unroll
            for (int q = 0; q < 8; ++q) {
                int idx = q * 256 + tid;   // 0..2047 (float4 units)
                int r   = idx >> 6;        // 0..31
                int c4  = idx & 63;
                float4 v = *(const float4*)(W3 + (size_t)(ks * 32 + r) * 5120
                                               + ch * 256 + c4 * 4);
                *(float4*)(w3s + r * 256 + c4 * 4) = v;
            }
            __syncthreads();

            for (int k = 0; k < 32; ++k) {
                float4 b  = *(const float4*)(w3s + k * 256 + ct * 4);
                const float* arow = &h2s[ks * 32 + k][et * 8];
                float4 a0 = *(const float4*)(arow);
                float4 a1 = *(const float4*)(arow + 4);
                float av[8] = {a0.x, a0.y, a0.z, a0.w, a1.x, a1.y, a1.z, a1.w};
                float bv[4] = {b.x, b.y, b.z, b.w};
                #pragma unroll
                for (int i = 0; i < 8; ++i)
                    #pragma unroll
                    for (int c = 0; c < 4; ++c)
                        acc[i][c] += av[i] * bv[c];
            }
        }
        __syncthreads();  // all w3s reads done before wt overwrite

        #pragma unroll
        for (int i = 0; i < 8; ++i) {
            int e = et * 8 + i;
            float4 v;
            v.x = acc[i][0] * 0.08838834764831845f;
            v.y = acc[i][1] * 0.08838834764831845f;
            v.z = acc[i][2] * 0.08838834764831845f;
            v.w = acc[i][3] * 0.08838834764831845f;
            *(float4*)(wt + e * 260 + ct * 4) = v;
        }
        __syncthreads();

        // epilogue: contract this chunk's 8 (p,u) rows with x2 -> d
        {
            int e = tid >> 3;                 // 0..31
            int q = tid & 7;                  // 0..7
            int p = ch >> 2;                  // wave-uniform
            int u = (ch & 3) * 8 + q;
            const float* wr = wt + e * 260 + q * 32;
            const float* x2 = em2 + (size_t)(e0 + e) * 128;
            float* dout = dws + (size_t)(e0 + e) * 352;
            if (p == 0 || p == 2) {
                float s = 0.f;
                #pragma unroll
                for (int v = 0; v < 32; ++v) s += wr[v] * x2[v];
                dout[(p == 0 ? 0 : 128) + u] = s;
            } else {
                float s0 = 0.f, s1 = 0.f, s2 = 0.f;
                #pragma unroll
                for (int v = 0; v < 32; ++v) {
                    float wv = wr[v];
                    const float* xv = x2 + 32 + v * 3;
                    s0 += wv * xv[0];
                    s1 += wv * xv[1];
                    s2 += wv * xv[2];
                }
                int off = (p == 1) ? 32 : (p == 3) ? 160 : 256;
                dout[off + u * 3 + 0] = s0;
                dout[off + u * 3 + 1] = s1;
                dout[off + u * 3 + 2] = s2;
            }
        }
    }
}

// cbuf layout per edge (352 floats):
//   c1[u]: [0+u]  c2[u][j]: [32+u*3+j]  c3[u][i]: [128+u*3+i]
//   c4[u]: [224+u]  c5[u][k]: [256+u*3+k]
__global__ __launch_bounds__(256, 4)
void finalize(const float* __restrict__ em1,   // [E][128]
              const float* __restrict__ dws,   // [E][352]
              const float* __restrict__ W0e,   // [64][32]
              const float* __restrict__ W1o,   // [64][32]
              const float* __restrict__ W1e,   // [32][32]
              float* __restrict__ out)         // [E][224]
{
    __shared__ float db[16 * 352];
    __shared__ float x1[16 * 128];
    __shared__ float cb[16 * 352];
    const int tid = threadIdx.x;
    const int e0  = blockIdx.x * 16;

    for (int idx = tid; idx < 16 * 352; idx += 256)
        db[idx] = dws[(size_t)e0 * 352 + idx];
    for (int idx = tid; idx < 16 * 128; idx += 256)
        x1[idx] = em1[(size_t)e0 * 128 + idx];
    __syncthreads();

    for (int idx = tid; idx < 16 * 352; idx += 256) {
        int e = idx / 352;
        int r = idx - e * 352;
        const float* d = db + e * 352;
        const float* x = x1 + e * 128;
        float val;
        if (r < 32) {                       // c1
            val = x[r] * d[r] * 0.17677669529663687f;
        } else if (r < 128) {               // c2
            int t = r - 32; int u = t / 3;
            val = x[u] * d[r] * 0.17677669529663687f;
        } else if (r < 224) {               // c3
            int t = r - 128; int u = t / 3; int i = t - u * 3;
            val = x[32 + u * 3 + i] * d[128 + u] * 0.17677669529663687f;
        } else if (r < 256) {               // c4
            int u = r - 224;
            const float* a = x + 32 + u * 3;
            const float* b = d + 160 + u * 3;
            val = (a[0] * b[0] + a[1] * b[1] + a[2] * b[2]) * 0.10206207261596575f;
        } else {                            // c5 = cross(x1_1[u], d4[u]) * 0.125
            int t = r - 256; int u = t / 3; int k = t - u * 3;
            const float* a = x + 32 + u * 3;
            const float* b = d + 256 + u * 3;
            int k1 = k + 1; if (k1 > 2) k1 -= 3;
            int k2 = k + 2; if (k2 > 2) k2 -= 3;
            val = (a[k1] * b[k2] - a[k2] * b[k1]) * 0.125f;
        }
        cb[e * 352 + r] = val;
    }
    __syncthreads();

    for (int idx = tid; idx < 16 * 224; idx += 256) {
        int e = idx / 224;
        int r = idx - e * 224;
        const float* c = cb + e * 352;
        float acc = 0.f;
        if (r < 32) {                       // out_0e
            int w = r;
            for (int u = 0; u < 32; ++u)
                acc += c[u] * W0e[u * 32 + w] + c[224 + u] * W0e[(32 + u) * 32 + w];
            acc *= 0.125f;
        } else if (r < 128) {               // out_1o (w*3+j)
            int t = r - 32; int w = t / 3; int j = t - w * 3;
            for (int u = 0; u < 32; ++u)
                acc += c[32 + u * 3 + j] * W1o[u * 32 + w]
                     + c[128 + u * 3 + j] * W1o[(32 + u) * 32 + w];
            acc *= 0.125f;
        } else {                            // out_1e (w*3+k)
            int t = r - 128; int w = t / 3; int k = t - w * 3;
            for (int u = 0; u < 32; ++u)
                acc += c[256 + u * 3 + k] * W1e[u * 32 + w];
            acc *= 0.17677669529663687f;
        }
        out[(size_t)e0 * 224 + idx] = acc;
    }
}

extern "C" void kernel_launch(void* const* d_in, const int* in_sizes, int n_in,
                              void* d_out, int out_size, void* d_ws, size_t ws_size,
                              hipStream_t stream) {
    const float* ef  = (const float*)d_in[0];   // edge_feats      [E][32]
    const float* em1 = (const float*)d_in[1];   // edge_messages1  [E][128]
    const float* em2 = (const float*)d_in[2];   // edge_messages2  [E][128]
    const float* nfs = (const float*)d_in[3];   // node_feats_sender   [E][128]
    const float* nfr = (const float*)d_in[4];   // node_feats_receiver [E][128]
    const float* Wn  = (const float*)d_in[5];   // [128][32]
    const float* W1  = (const float*)d_in[6];   // [96][128]
    const float* W2  = (const float*)d_in[7];   // [128][128]
    const float* W3  = (const float*)d_in[8];   // [128][5120]
    const float* W0e = (const float*)d_in[9];   // [64][32]
    const float* W1o = (const float*)d_in[10];  // [64][32]
    const float* W1e = (const float*)d_in[11];  // [32][32]
    float* out = (float*)d_out;
    float* dws = (float*)d_ws;                  // [E][352] = 56.3 MB

    const int E = in_sizes[0] / 32;             // 40000

    fused_main<<<E / TILE_E, THREADS, 0, stream>>>(ef, em2, nfs, nfr,
                                                   Wn, W1, W2, W3, dws);
    finalize<<<E / 16, THREADS, 0, stream>>>(em1, dws, W0e, W1o, W1e, out);
}

// Round 2
// 673.834 us; speedup vs baseline: 3.7001x; 3.7001x over previous
//
#include <hip/hip_runtime.h>
#include <hip/hip_bf16.h>
#include <math.h>

typedef __attribute__((ext_vector_type(8))) short bf16x8;   // 8 bf16 = 4 VGPR
typedef __attribute__((ext_vector_type(4))) float f32x4;

__device__ __forceinline__ float silu_f(float x) {
    return x / (1.0f + expf(-x));
}

// ---------------------------------------------------------------------------
// K2: W3 [128][5120] f32  ->  W3T [5120][128] bf16
// ---------------------------------------------------------------------------
__global__ __launch_bounds__(256)
void w3_transpose(const float* __restrict__ W3, ushort* __restrict__ w3t) {
    __shared__ float t[32][65];
    const int tid = threadIdx.x;
    const int cb = blockIdx.x * 64;     // 80 blocks
    const int kb = blockIdx.y * 32;     // 4 blocks
    #pragma unroll
    for (int it = 0; it < 8; ++it) {
        int idx = it * 256 + tid;       // 0..2047
        int r = idx >> 6, c = idx & 63;
        t[r][c] = W3[(size_t)(kb + r) * 5120 + cb + c];
    }
    __syncthreads();
    #pragma unroll
    for (int it = 0; it < 8; ++it) {
        int idx = it * 256 + tid;
        int c = idx >> 5, k = idx & 31;
        __hip_bfloat16 b = __float2bfloat16(t[k][c]);
        w3t[(size_t)(cb + c) * 128 + kb + k] = *(ushort*)&b;
    }
}

// ---------------------------------------------------------------------------
// K1: MLP  ->  h2 bf16 [E][128]
// ---------------------------------------------------------------------------
__global__ __launch_bounds__(256, 2)
void mlp_kernel(const float* __restrict__ ef,     // [E][32]
                const float* __restrict__ nfs,    // [E][128]
                const float* __restrict__ nfr,    // [E][128]
                const float* __restrict__ Wn,     // [128][32]
                const float* __restrict__ W1,     // [96][128]
                const float* __restrict__ W2,     // [128][128]
                ushort* __restrict__ h2b)         // [E][128] bf16
{
    __shared__ __align__(16) float scal[32][100];
    __shared__ __align__(16) float Cbuf[8192];    // nf[2][32][128] / h1[32][128]
    const int tid = threadIdx.x;
    const int e0  = blockIdx.x * 32;

    float* nf = Cbuf;
    float* h1 = Cbuf;

    #pragma unroll
    for (int q = 0; q < 8; ++q) {
        int idx = q * 256 + tid;
        int sel = idx >> 10;
        int e   = (idx >> 5) & 31;
        int t4  = idx & 31;
        const float* src = sel ? nfr : nfs;
        float4 v = *(const float4*)(src + (size_t)(e0 + e) * 128 + t4 * 4);
        *(float4*)(nf + sel * 4096 + e * 128 + t4 * 4) = v;
    }
    #pragma unroll
    for (int q = 0; q < 4; ++q) {
        int idx = q * 256 + tid;
        int e = idx >> 5, j = idx & 31;
        scal[e][64 + j] = ef[(size_t)(e0 + e) * 32 + j];
    }
    __syncthreads();

    #pragma unroll
    for (int q = 0; q < 8; ++q) {
        int idx = q * 256 + tid;
        int sel = idx >> 10;
        int e   = (idx >> 5) & 31;
        int j   = idx & 31;
        const float* nrow = nf + sel * 4096 + e * 128;
        float acc = 0.f;
        for (int t = 0; t < 128; ++t)
            acc += nrow[t] * Wn[t * 32 + j];
        scal[e][sel * 32 + j] = acc * 0.08838834764831845f;
    }
    __syncthreads();

    #pragma unroll
    for (int q = 0; q < 16; ++q) {
        int idx = q * 256 + tid;
        int e = idx >> 7, j = idx & 127;
        float acc = 0.f;
        for (int t = 0; t < 96; ++t)
            acc += scal[e][t] * W1[t * 128 + j];
        h1[e * 128 + j] = silu_f(acc * 0.10206207261596575f);
    }
    __syncthreads();

    #pragma unroll
    for (int q = 0; q < 16; ++q) {
        int idx = q * 256 + tid;
        int e = idx >> 7, j = idx & 127;
        float acc = 0.f;
        for (int t = 0; t < 128; ++t)
            acc += h1[e * 128 + t] * W2[t * 128 + j];
        __hip_bfloat16 b = __float2bfloat16(silu_f(acc * 0.08838834764831845f));
        h2b[(size_t)(e0 + e) * 128 + j] = *(ushort*)&b;
    }
}

// ---------------------------------------------------------------------------
// K3: MFMA GEMM (w = h2 @ W3 / sqrt(128)) fused with x2 contraction -> d bf16
//   BM=64 edges/block, 8 waves, N-chunks of 256 cols, K=128.
//   Wave wv owns cols [wv*32, wv*32+32) of each chunk = one (p,u) group.
//   No __syncthreads: accum->LDS->contract is wave-local.
// d layout per edge (352 bf16): d0 u | d1 u*3+j @32 | d2 @128 | d3 @160 | d4 @256
// ---------------------------------------------------------------------------
__global__ __launch_bounds__(512, 2)
void gemm_contract(const ushort* __restrict__ h2b,   // [E][128] bf16
                   const ushort* __restrict__ w3t,   // [5120][128] bf16
                   const float*  __restrict__ em2,   // [E][128]
                   __hip_bfloat16* __restrict__ dws) // [E][352] bf16
{
    __shared__ float wlds[8 * 64 * 32];              // 64 KB, per-wave 8 KB
    const int tid  = threadIdx.x;
    const int lane = tid & 63;
    const int wv   = tid >> 6;
    const int l15  = lane & 15;
    const int lg   = lane >> 4;
    const int e0   = blockIdx.x * 64;

    // A fragments: loaded once, reused across all 20 chunks.
    bf16x8 a[4][4];
    #pragma unroll
    for (int mi = 0; mi < 4; ++mi)
        #pragma unroll
        for (int ks = 0; ks < 4; ++ks)
            a[mi][ks] = *(const bf16x8*)(h2b + (size_t)(e0 + mi * 16 + l15) * 128
                                             + ks * 32 + lg * 8);

    f32x4 acc[4][2];
    bf16x8 b0[2][4], b1[2][4];

    auto loadB = [&](bf16x8 (&b)[2][4], int ch) {
        int colbase = ch * 256 + wv * 32;
        #pragma unroll
        for (int nf = 0; nf < 2; ++nf)
            #pragma unroll
            for (int ks = 0; ks < 4; ++ks)
                b[nf][ks] = *(const bf16x8*)(w3t
                    + (size_t)(colbase + nf * 16 + l15) * 128 + ks * 32 + lg * 8);
    };

    auto mfma_step = [&](bf16x8 (&b)[2][4]) {
        #pragma unroll
        for (int mi = 0; mi < 4; ++mi)
            #pragma unroll
            for (int nf = 0; nf < 2; ++nf)
                acc[mi][nf] = (f32x4){0.f, 0.f, 0.f, 0.f};
        #pragma unroll
        for (int ks = 0; ks < 4; ++ks)
            #pragma unroll
            for (int mi = 0; mi < 4; ++mi)
                #pragma unroll
                for (int nf = 0; nf < 2; ++nf)
                    acc[mi][nf] = __builtin_amdgcn_mfma_f32_16x16x32_bf16(
                        a[mi][ks], b[nf][ks], acc[mi][nf], 0, 0, 0);
    };

    auto tail = [&](int ch) {
        float* wb = wlds + wv * 2048;
        // accum -> wave-local LDS, column rotated by 2*row (bank spread)
        #pragma unroll
        for (int mi = 0; mi < 4; ++mi)
            #pragma unroll
            for (int nf = 0; nf < 2; ++nf) {
                int vcol = nf * 16 + l15;
                #pragma unroll
                for (int r = 0; r < 4; ++r) {
                    int row = mi * 16 + lg * 4 + r;
                    wb[row * 32 + ((vcol + 2 * row) & 31)] = acc[mi][nf][r];
                }
            }
        // contraction: lane = edge, this wave's (p,u)
        const float* wrd = wb + lane * 32;
        const float* x2  = em2 + (size_t)(e0 + lane) * 128;
        int pu = ch * 8 + wv;
        int p = pu >> 5, u = pu & 31;
        __hip_bfloat16* dout = dws + (size_t)(e0 + lane) * 352;
        const float sc = 0.08838834764831845f;   // 1/sqrt(128)
        if (p == 0 || p == 2) {
            float s = 0.f;
            #pragma unroll
            for (int q2 = 0; q2 < 16; ++q2) {
                float2 w2 = *(const float2*)(wrd + ((q2 * 2 + lane * 2) & 31));
                s += w2.x * x2[q2 * 2] + w2.y * x2[q2 * 2 + 1];
            }
            dout[(p == 0 ? 0 : 128) + u] = __float2bfloat16(s * sc);
        } else {
            float s0 = 0.f, s1 = 0.f, s2 = 0.f;
            #pragma unroll
            for (int q2 = 0; q2 < 16; ++q2) {
                float2 w2 = *(const float2*)(wrd + ((q2 * 2 + lane * 2) & 31));
                const float* xa = x2 + 32 + q2 * 6;
                s0 += w2.x * xa[0] + w2.y * xa[3];
                s1 += w2.x * xa[1] + w2.y * xa[4];
                s2 += w2.x * xa[2] + w2.y * xa[5];
            }
            int off = (p == 1) ? 32 : (p == 3) ? 160 : 256;
            dout[off + u * 3 + 0] = __float2bfloat16(s0 * sc);
            dout[off + u * 3 + 1] = __float2bfloat16(s1 * sc);
            dout[off + u * 3 + 2] = __float2bfloat16(s2 * sc);
        }
    };

    loadB(b0, 0);
    #pragma unroll 1
    for (int ch = 0; ch < 20; ch += 2) {
        mfma_step(b0);
        loadB(b1, ch + 1);               // prefetch overlaps epilogue
        tail(ch);
        mfma_step(b1);
        if (ch + 2 < 20) loadB(b0, ch + 2);
        tail(ch + 1);
    }
}

// ---------------------------------------------------------------------------
// K4: finalize (c-values from d and x1, then small output matmuls)
// ---------------------------------------------------------------------------
__global__ __launch_bounds__(256, 4)
void finalize(const float* __restrict__ em1,             // [E][128]
              const __hip_bfloat16* __restrict__ dwsb,   // [E][352] bf16
              const float* __restrict__ W0e,             // [64][32]
              const float* __restrict__ W1o,             // [64][32]
              const float* __restrict__ W1e,             // [32][32]
              float* __restrict__ out)                   // [E][224]
{
    __shared__ float db[16 * 352];
    __shared__ float x1[16 * 128];
    __shared__ float cb[16 * 352];
    const int tid = threadIdx.x;
    const int e0  = blockIdx.x * 16;

    for (int idx = tid; idx < 16 * 352; idx += 256)
        db[idx] = __bfloat162float(dwsb[(size_t)e0 * 352 + idx]);
    for (int idx = tid; idx < 16 * 128; idx += 256)
        x1[idx] = em1[(size_t)e0 * 128 + idx];
    __syncthreads();

    for (int idx = tid; idx < 16 * 352; idx += 256) {
        int e = idx / 352;
        int r = idx - e * 352;
        const float* d = db + e * 352;
        const float* x = x1 + e * 128;
        float val;
        if (r < 32) {
            val = x[r] * d[r] * 0.17677669529663687f;
        } else if (r < 128) {
            int t = r - 32; int u = t / 3;
            val = x[u] * d[r] * 0.17677669529663687f;
        } else if (r < 224) {
            int t = r - 128; int u = t / 3; int i = t - u * 3;
            val = x[32 + u * 3 + i] * d[128 + u] * 0.17677669529663687f;
        } else if (r < 256) {
            int u = r - 224;
            const float* aa = x + 32 + u * 3;
            const float* bb = d + 160 + u * 3;
            val = (aa[0] * bb[0] + aa[1] * bb[1] + aa[2] * bb[2]) * 0.10206207261596575f;
        } else {
            int t = r - 256; int u = t / 3; int k = t - u * 3;
            const float* aa = x + 32 + u * 3;
            const float* bb = d + 256 + u * 3;
            int k1 = k + 1; if (k1 > 2) k1 -= 3;
            int k2 = k + 2; if (k2 > 2) k2 -= 3;
            val = (aa[k1] * bb[k2] - aa[k2] * bb[k1]) * 0.125f;
        }
        cb[e * 352 + r] = val;
    }
    __syncthreads();

    for (int idx = tid; idx < 16 * 224; idx += 256) {
        int e = idx / 224;
        int r = idx - e * 224;
        const float* c = cb + e * 352;
        float acc = 0.f;
        if (r < 32) {
            int w = r;
            for (int u = 0; u < 32; ++u)
                acc += c[u] * W0e[u * 32 + w] + c[224 + u] * W0e[(32 + u) * 32 + w];
            acc *= 0.125f;
        } else if (r < 128) {
            int t = r - 32; int w = t / 3; int j = t - w * 3;
            for (int u = 0; u < 32; ++u)
                acc += c[32 + u * 3 + j] * W1o[u * 32 + w]
                     + c[128 + u * 3 + j] * W1o[(32 + u) * 32 + w];
            acc *= 0.125f;
        } else {
            int t = r - 128; int w = t / 3; int k = t - w * 3;
            for (int u = 0; u < 32; ++u)
                acc += c[256 + u * 3 + k] * W1e[u * 32 + w];
            acc *= 0.17677669529663687f;
        }
        out[(size_t)e0 * 224 + idx] = acc;
    }
}

// ---------------------------------------------------------------------------
extern "C" void kernel_launch(void* const* d_in, const int* in_sizes, int n_in,
                              void* d_out, int out_size, void* d_ws, size_t ws_size,
                              hipStream_t stream) {
    const float* ef  = (const float*)d_in[0];
    const float* em1 = (const float*)d_in[1];
    const float* em2 = (const float*)d_in[2];
    const float* nfs = (const float*)d_in[3];
    const float* nfr = (const float*)d_in[4];
    const float* Wn  = (const float*)d_in[5];
    const float* W1  = (const float*)d_in[6];
    const float* W2  = (const float*)d_in[7];
    const float* W3  = (const float*)d_in[8];
    const float* W0e = (const float*)d_in[9];
    const float* W1o = (const float*)d_in[10];
    const float* W1e = (const float*)d_in[11];
    float* out = (float*)d_out;

    const int E = in_sizes[0] / 32;   // 40000

    // ws layout (bytes): dws bf16 [E][352] | h2b bf16 [E][128] | w3t bf16 [5120][128]
    char* ws = (char*)d_ws;
    __hip_bfloat16* dws = (__hip_bfloat16*)ws;
    ushort* h2b = (ushort*)(ws + (size_t)E * 352 * 2);
    ushort* w3t = (ushort*)(ws + (size_t)E * 352 * 2 + (size_t)E * 128 * 2);

    w3_transpose<<<dim3(80, 4), 256, 0, stream>>>(W3, w3t);
    mlp_kernel<<<E / 32, 256, 0, stream>>>(ef, nfs, nfr, Wn, W1, W2, h2b);
    gemm_contract<<<E / 64, 512, 0, stream>>>(h2b, w3t, em2, dws);
    finalize<<<E / 16, 256, 0, stream>>>(em1, dws, W0e, W1o, W1e, out);
}

// Round 3
// 282.644 us; speedup vs baseline: 8.8212x; 2.3840x over previous
//
#include <hip/hip_runtime.h>
#include <hip/hip_bf16.h>
#include <math.h>

typedef __attribute__((ext_vector_type(8))) short bf16x8;
typedef __attribute__((ext_vector_type(4))) float f32x4;

__device__ __forceinline__ float silu_f(float x) {
    return x / (1.0f + expf(-x));
}
__device__ __forceinline__ ushort f2b(float x) {
    __hip_bfloat16 b = __float2bfloat16(x);
    return *(ushort*)&b;
}

// ---------------------------------------------------------------------------
// prep: WnT [32][128], W1T [128][96], W2T [128][128] (all bf16 transposes)
// ---------------------------------------------------------------------------
__global__ __launch_bounds__(256)
void prep_weights(const float* __restrict__ Wn, const float* __restrict__ W1,
                  const float* __restrict__ W2, ushort* __restrict__ WnT,
                  ushort* __restrict__ W1T, ushort* __restrict__ W2T) {
    int idx = blockIdx.x * 256 + threadIdx.x;   // 128 blocks -> 32768
    if (idx < 4096) {
        int n = idx >> 7, k = idx & 127;
        WnT[n * 128 + k] = f2b(Wn[k * 32 + n]);
    } else if (idx < 16384) {
        int t = idx - 4096; int n = t / 96, k = t - n * 96;
        W1T[n * 96 + k] = f2b(W1[k * 128 + n]);
    } else {
        int t = idx - 16384; int n = t >> 7, k = t & 127;
        W2T[n * 128 + k] = f2b(W2[k * 128 + n]);
    }
}

// ---------------------------------------------------------------------------
// W3 [128][5120] f32 -> W3T [5120][128] bf16
// ---------------------------------------------------------------------------
__global__ __launch_bounds__(256)
void w3_transpose(const float* __restrict__ W3, ushort* __restrict__ w3t) {
    __shared__ float t[32][65];
    const int tid = threadIdx.x;
    const int cb = blockIdx.x * 64;
    const int kb = blockIdx.y * 32;
    #pragma unroll
    for (int it = 0; it < 8; ++it) {
        int idx = it * 256 + tid;
        int r = idx >> 6, c = idx & 63;
        t[r][c] = W3[(size_t)(kb + r) * 5120 + cb + c];
    }
    __syncthreads();
    #pragma unroll
    for (int it = 0; it < 8; ++it) {
        int idx = it * 256 + tid;
        int c = idx >> 5, k = idx & 31;
        w3t[(size_t)(cb + c) * 128 + kb + k] = f2b(t[k][c]);
    }
}

// ---------------------------------------------------------------------------
// MLP via MFMA: 64 edges/block, 4 waves.  -> h2 bf16 [E][128]
// ---------------------------------------------------------------------------
__global__ __launch_bounds__(256)
void mlp_mfma(const float* __restrict__ ef, const float* __restrict__ nfs,
              const float* __restrict__ nfr, const ushort* __restrict__ WnT,
              const ushort* __restrict__ W1T, const ushort* __restrict__ W2T,
              ushort* __restrict__ h2b) {
    __shared__ ushort scal[64 * 104];    // [e][96 used]: send|recv|ef (bf16)
    __shared__ ushort h1b[64 * 136];
    __shared__ ushort h2s[64 * 128];
    const int tid = threadIdx.x;
    const int lane = tid & 63, wv = tid >> 6;
    const int l15 = lane & 15, lg = lane >> 4;
    const int e0 = blockIdx.x * 64;

    // stage ef -> scal cols 64..95
    #pragma unroll
    for (int it = 0; it < 8; ++it) {
        int idx = it * 256 + tid;
        int e = idx >> 5, j = idx & 31;
        scal[e * 104 + 64 + j] = f2b(ef[(size_t)(e0 + e) * 32 + j]);
    }

    // step 1: s_send / s_recv = nf @ Wn / sqrt(128)
    f32x4 acc1[2][2];
    #pragma unroll
    for (int h = 0; h < 2; ++h)
        #pragma unroll
        for (int nf = 0; nf < 2; ++nf)
            acc1[h][nf] = (f32x4){0.f, 0.f, 0.f, 0.f};
    const int erow = e0 + wv * 16 + l15;
    #pragma unroll
    for (int h = 0; h < 2; ++h) {
        const float* src = h ? nfr : nfs;
        #pragma unroll
        for (int ks = 0; ks < 4; ++ks) {
            float4 va = *(const float4*)(src + (size_t)erow * 128 + ks * 32 + lg * 8);
            float4 vb = *(const float4*)(src + (size_t)erow * 128 + ks * 32 + lg * 8 + 4);
            bf16x8 a;
            a[0] = (short)f2b(va.x); a[1] = (short)f2b(va.y);
            a[2] = (short)f2b(va.z); a[3] = (short)f2b(va.w);
            a[4] = (short)f2b(vb.x); a[5] = (short)f2b(vb.y);
            a[6] = (short)f2b(vb.z); a[7] = (short)f2b(vb.w);
            #pragma unroll
            for (int nf = 0; nf < 2; ++nf) {
                bf16x8 b = *(const bf16x8*)(WnT + (nf * 16 + l15) * 128 + ks * 32 + lg * 8);
                acc1[h][nf] = __builtin_amdgcn_mfma_f32_16x16x32_bf16(a, b, acc1[h][nf], 0, 0, 0);
            }
        }
    }
    #pragma unroll
    for (int h = 0; h < 2; ++h)
        #pragma unroll
        for (int nf = 0; nf < 2; ++nf)
            #pragma unroll
            for (int r = 0; r < 4; ++r) {
                int e = wv * 16 + lg * 4 + r;
                scal[e * 104 + h * 32 + nf * 16 + l15] =
                    f2b(acc1[h][nf][r] * 0.08838834764831845f);
            }
    __syncthreads();

    // step 2: h1 = silu(scal @ W1 / sqrt(96))
    f32x4 acc2[8];
    #pragma unroll
    for (int nf = 0; nf < 8; ++nf) acc2[nf] = (f32x4){0.f, 0.f, 0.f, 0.f};
    #pragma unroll
    for (int ks = 0; ks < 3; ++ks) {
        bf16x8 a = *(const bf16x8*)&scal[(wv * 16 + l15) * 104 + ks * 32 + lg * 8];
        #pragma unroll
        for (int nf = 0; nf < 8; ++nf) {
            bf16x8 b = *(const bf16x8*)(W1T + (nf * 16 + l15) * 96 + ks * 32 + lg * 8);
            acc2[nf] = __builtin_amdgcn_mfma_f32_16x16x32_bf16(a, b, acc2[nf], 0, 0, 0);
        }
    }
    #pragma unroll
    for (int nf = 0; nf < 8; ++nf)
        #pragma unroll
        for (int r = 0; r < 4; ++r) {
            int e = wv * 16 + lg * 4 + r;
            h1b[e * 136 + nf * 16 + l15] =
                f2b(silu_f(acc2[nf][r] * 0.10206207261596575f));
        }
    __syncthreads();

    // step 3: h2 = silu(h1 @ W2 / sqrt(128))
    f32x4 acc3[8];
    #pragma unroll
    for (int nf = 0; nf < 8; ++nf) acc3[nf] = (f32x4){0.f, 0.f, 0.f, 0.f};
    #pragma unroll
    for (int ks = 0; ks < 4; ++ks) {
        bf16x8 a = *(const bf16x8*)&h1b[(wv * 16 + l15) * 136 + ks * 32 + lg * 8];
        #pragma unroll
        for (int nf = 0; nf < 8; ++nf) {
            bf16x8 b = *(const bf16x8*)(W2T + (nf * 16 + l15) * 128 + ks * 32 + lg * 8);
            acc3[nf] = __builtin_amdgcn_mfma_f32_16x16x32_bf16(a, b, acc3[nf], 0, 0, 0);
        }
    }
    #pragma unroll
    for (int nf = 0; nf < 8; ++nf)
        #pragma unroll
        for (int r = 0; r < 4; ++r) {
            int e = wv * 16 + lg * 4 + r;
            h2s[e * 128 + nf * 16 + l15] =
                f2b(silu_f(acc3[nf][r] * 0.08838834764831845f));
        }
    __syncthreads();

    // coalesced copy out
    #pragma unroll
    for (int it = 0; it < 4; ++it) {
        int idx = it * 256 + tid;            // 1024 chunks of 8 bf16
        bf16x8 v = *(const bf16x8*)&h2s[idx * 8];
        *(bf16x8*)(h2b + (size_t)e0 * 128 + idx * 8) = v;
    }
}

// ---------------------------------------------------------------------------
// GEMM (swapped): C[m=(p,u,v)][e] = sum_k W3T[m][k] h2[e][k], fused contraction
// grid 625, block 512 (8 waves). Wave owns 64 M-rows per M-iter, 10 M-iters.
// ---------------------------------------------------------------------------
__global__ __launch_bounds__(512)
void gemm_contract(const ushort* __restrict__ h2b, const ushort* __restrict__ w3t,
                   const float* __restrict__ em2, __hip_bfloat16* __restrict__ dws) {
    __shared__ ushort h2s[64 * 128];      // XOR-swizzled 16B chunks, 16 KB
    __shared__ float x2s[64 * 129];       // padded, 33 KB
    const int tid = threadIdx.x;
    const int lane = tid & 63, wv = tid >> 6;
    const int l15 = lane & 15, lg = lane >> 4;
    const int e0 = blockIdx.x * 64;

    // stage h2 tile with chunk-XOR swizzle
    #pragma unroll
    for (int it = 0; it < 2; ++it) {
        int idx = it * 512 + tid;          // 1024 chunk slots
        int e = idx >> 4, c = idx & 15;
        bf16x8 v = *(const bf16x8*)(h2b + (size_t)(e0 + e) * 128 + c * 8);
        *(bf16x8*)&h2s[(e * 16 + (c ^ (e & 15))) * 8] = v;
    }
    // stage x2 (em2) rows, stride 129
    #pragma unroll
    for (int it = 0; it < 4; ++it) {
        int idx = it * 512 + tid;          // 2048 float4
        int e = idx >> 5, c4 = idx & 31;
        float4 v = *(const float4*)(em2 + (size_t)(e0 + e) * 128 + c4 * 4);
        float* dst = &x2s[e * 129 + c4 * 4];
        dst[0] = v.x; dst[1] = v.y; dst[2] = v.z; dst[3] = v.w;
    }
    __syncthreads();

    const float sc = 0.08838834764831845f;

    #pragma unroll 1
    for (int mt = 0; mt < 10; ++mt) {
        const int mbase = mt * 512 + wv * 64;
        const int p = mbase >> 10;
        const int ubase = (mbase & 1023) >> 5;

        f32x4 acc[4][4];
        #pragma unroll
        for (int mi = 0; mi < 4; ++mi)
            #pragma unroll
            for (int nf = 0; nf < 4; ++nf)
                acc[mi][nf] = (f32x4){0.f, 0.f, 0.f, 0.f};

        bf16x8 a0[4], a1[4];
        #pragma unroll
        for (int mi = 0; mi < 4; ++mi)
            a0[mi] = *(const bf16x8*)(w3t + (size_t)(mbase + mi * 16 + l15) * 128 + lg * 8);

        #pragma unroll
        for (int ks = 0; ks < 4; ++ks) {
            bf16x8* ac = (ks & 1) ? a1 : a0;
            bf16x8* an = (ks & 1) ? a0 : a1;
            if (ks < 3) {
                #pragma unroll
                for (int mi = 0; mi < 4; ++mi)
                    an[mi] = *(const bf16x8*)(w3t
                        + (size_t)(mbase + mi * 16 + l15) * 128 + (ks + 1) * 32 + lg * 8);
            }
            #pragma unroll
            for (int nf = 0; nf < 4; ++nf) {
                int e = nf * 16 + l15;
                bf16x8 b = *(const bf16x8*)&h2s[(e * 16 + ((ks * 4 + lg) ^ l15)) * 8];
                #pragma unroll
                for (int mi = 0; mi < 4; ++mi)
                    acc[mi][nf] = __builtin_amdgcn_mfma_f32_16x16x32_bf16(
                        ac[mi], b, acc[mi][nf], 0, 0, 0);
            }
        }

        // tail: contract over v (rows), edge = l15, reduce over lg via shfl
        if (p == 0 || p == 2) {
            const int off = (p == 0) ? 0 : 128;
            #pragma unroll
            for (int nf = 0; nf < 4; ++nf) {
                const int e = nf * 16 + l15;
                const float* xr = &x2s[e * 129];
                float xa[4], xb[4];
                #pragma unroll
                for (int r = 0; r < 4; ++r) {
                    xa[r] = xr[lg * 4 + r];
                    xb[r] = xr[16 + lg * 4 + r];
                }
                #pragma unroll
                for (int g = 0; g < 2; ++g) {
                    float s = 0.f;
                    #pragma unroll
                    for (int r = 0; r < 4; ++r)
                        s += acc[2 * g][nf][r] * xa[r] + acc[2 * g + 1][nf][r] * xb[r];
                    s += __shfl_xor(s, 16);
                    s += __shfl_xor(s, 32);
                    if (lg == 0)
                        dws[(size_t)(e0 + e) * 352 + off + ubase + g] = __float2bfloat16(s * sc);
                }
            }
        } else {
            const int off = (p == 1) ? 32 : (p == 3) ? 160 : 256;
            #pragma unroll
            for (int nf = 0; nf < 4; ++nf) {
                const int e = nf * 16 + l15;
                const float* xr = &x2s[e * 129];
                float xa[4][3], xb[4][3];
                #pragma unroll
                for (int r = 0; r < 4; ++r)
                    #pragma unroll
                    for (int j = 0; j < 3; ++j) {
                        xa[r][j] = xr[32 + (lg * 4 + r) * 3 + j];
                        xb[r][j] = xr[32 + (16 + lg * 4 + r) * 3 + j];
                    }
                #pragma unroll
                for (int g = 0; g < 2; ++g) {
                    float s0 = 0.f, s1 = 0.f, s2 = 0.f;
                    #pragma unroll
                    for (int r = 0; r < 4; ++r) {
                        float wa = acc[2 * g][nf][r], wb = acc[2 * g + 1][nf][r];
                        s0 += wa * xa[r][0] + wb * xb[r][0];
                        s1 += wa * xa[r][1] + wb * xb[r][1];
                        s2 += wa * xa[r][2] + wb * xb[r][2];
                    }
                    s0 += __shfl_xor(s0, 16); s0 += __shfl_xor(s0, 32);
                    s1 += __shfl_xor(s1, 16); s1 += __shfl_xor(s1, 32);
                    s2 += __shfl_xor(s2, 16); s2 += __shfl_xor(s2, 32);
                    if (lg == 0) {
                        int u = ubase + g;
                        __hip_bfloat16* dout = dws + (size_t)(e0 + e) * 352 + off + u * 3;
                        dout[0] = __float2bfloat16(s0 * sc);
                        dout[1] = __float2bfloat16(s1 * sc);
                        dout[2] = __float2bfloat16(s2 * sc);
                    }
                }
            }
        }
    }
}

// ---------------------------------------------------------------------------
// finalize (unchanged from round 2)
// ---------------------------------------------------------------------------
__global__ __launch_bounds__(256, 4)
void finalize(const float* __restrict__ em1,
              const __hip_bfloat16* __restrict__ dwsb,
              const float* __restrict__ W0e, const float* __restrict__ W1o,
              const float* __restrict__ W1e, float* __restrict__ out) {
    __shared__ float db[16 * 352];
    __shared__ float x1[16 * 128];
    __shared__ float cb[16 * 352];
    const int tid = threadIdx.x;
    const int e0 = blockIdx.x * 16;

    for (int idx = tid; idx < 16 * 352; idx += 256)
        db[idx] = __bfloat162float(dwsb[(size_t)e0 * 352 + idx]);
    for (int idx = tid; idx < 16 * 128; idx += 256)
        x1[idx] = em1[(size_t)e0 * 128 + idx];
    __syncthreads();

    for (int idx = tid; idx < 16 * 352; idx += 256) {
        int e = idx / 352;
        int r = idx - e * 352;
        const float* d = db + e * 352;
        const float* x = x1 + e * 128;
        float val;
        if (r < 32) {
            val = x[r] * d[r] * 0.17677669529663687f;
        } else if (r < 128) {
            int t = r - 32; int u = t / 3;
            val = x[u] * d[r] * 0.17677669529663687f;
        } else if (r < 224) {
            int t = r - 128; int u = t / 3; int i = t - u * 3;
            val = x[32 + u * 3 + i] * d[128 + u] * 0.17677669529663687f;
        } else if (r < 256) {
            int u = r - 224;
            const float* aa = x + 32 + u * 3;
            const float* bb = d + 160 + u * 3;
            val = (aa[0] * bb[0] + aa[1] * bb[1] + aa[2] * bb[2]) * 0.10206207261596575f;
        } else {
            int t = r - 256; int u = t / 3; int k = t - u * 3;
            const float* aa = x + 32 + u * 3;
            const float* bb = d + 256 + u * 3;
            int k1 = k + 1; if (k1 > 2) k1 -= 3;
            int k2 = k + 2; if (k2 > 2) k2 -= 3;
            val = (aa[k1] * bb[k2] - aa[k2] * bb[k1]) * 0.125f;
        }
        cb[e * 352 + r] = val;
    }
    __syncthreads();

    for (int idx = tid; idx < 16 * 224; idx += 256) {
        int e = idx / 224;
        int r = idx - e * 224;
        const float* c = cb + e * 352;
        float acc = 0.f;
        if (r < 32) {
            int w = r;
            for (int u = 0; u < 32; ++u)
                acc += c[u] * W0e[u * 32 + w] + c[224 + u] * W0e[(32 + u) * 32 + w];
            acc *= 0.125f;
        } else if (r < 128) {
            int t = r - 32; int w = t / 3; int j = t - w * 3;
            for (int u = 0; u < 32; ++u)
                acc += c[32 + u * 3 + j] * W1o[u * 32 + w]
                     + c[128 + u * 3 + j] * W1o[(32 + u) * 32 + w];
            acc *= 0.125f;
        } else {
            int t = r - 128; int w = t / 3; int k = t - w * 3;
            for (int u = 0; u < 32; ++u)
                acc += c[256 + u * 3 + k] * W1e[u * 32 + w];
            acc *= 0.17677669529663687f;
        }
        out[(size_t)e0 * 224 + idx] = acc;
    }
}

// ---------------------------------------------------------------------------
extern "C" void kernel_launch(void* const* d_in, const int* in_sizes, int n_in,
                              void* d_out, int out_size, void* d_ws, size_t ws_size,
                              hipStream_t stream) {
    const float* ef  = (const float*)d_in[0];
    const float* em1 = (const float*)d_in[1];
    const float* em2 = (const float*)d_in[2];
    const float* nfs = (const float*)d_in[3];
    const float* nfr = (const float*)d_in[4];
    const float* Wn  = (const float*)d_in[5];
    const float* W1  = (const float*)d_in[6];
    const float* W2  = (const float*)d_in[7];
    const float* W3  = (const float*)d_in[8];
    const float* W0e = (const float*)d_in[9];
    const float* W1o = (const float*)d_in[10];
    const float* W1e = (const float*)d_in[11];
    float* out = (float*)d_out;

    const int E = in_sizes[0] / 32;   // 40000

    // ws layout: dws bf16 [E][352] | h2b bf16 [E][128] | w3t [5120][128] |
    //            WnT [32][128] | W1T [128][96] | W2T [128][128]   (~39.8 MB)
    char* ws = (char*)d_ws;
    __hip_bfloat16* dws = (__hip_bfloat16*)ws;
    size_t off = (size_t)E * 352 * 2;
    ushort* h2b = (ushort*)(ws + off);           off += (size_t)E * 128 * 2;
    ushort* w3t = (ushort*)(ws + off);           off += (size_t)5120 * 128 * 2;
    ushort* WnT = (ushort*)(ws + off);           off += 32 * 128 * 2;
    ushort* W1T = (ushort*)(ws + off);           off += 128 * 96 * 2;
    ushort* W2T = (ushort*)(ws + off);

    prep_weights<<<128, 256, 0, stream>>>(Wn, W1, W2, WnT, W1T, W2T);
    w3_transpose<<<dim3(80, 4), 256, 0, stream>>>(W3, w3t);
    mlp_mfma<<<E / 64, 256, 0, stream>>>(ef, nfs, nfr, WnT, W1T, W2T, h2b);
    gemm_contract<<<E / 64, 512, 0, stream>>>(h2b, w3t, em2, dws);
    finalize<<<E / 16, 256, 0, stream>>>(em1, dws, W0e, W1o, W1e, out);
}